// Round 1
// baseline (685.818 us; speedup 1.0000x reference)
//
#include <hip/hip_runtime.h>
#include <hip/hip_bf16.h>

typedef unsigned short u16;
typedef __bf16 bf16x8 __attribute__((ext_vector_type(8)));
typedef unsigned short u16x8 __attribute__((ext_vector_type(8)));
typedef float f32x4 __attribute__((ext_vector_type(4)));

#define SQHF 0.70710678118654752440f

__device__ __forceinline__ u16 f2bf(float f) {
  __hip_bfloat16 h = __float2bfloat16(f);
  return __builtin_bit_cast(u16, h);
}
__device__ __forceinline__ float bf2f(u16 u) {
  unsigned x = ((unsigned)u) << 16;
  return __builtin_bit_cast(float, x);
}
__device__ __forceinline__ void split2(float v, u16& hi, u16& lo) {
  hi = f2bf(v);
  lo = f2bf(v - bf2f(hi));
}

// async global->LDS, 16B per lane; LDS dest is wave-uniform base + lane*16
__device__ __forceinline__ void gload_lds16(const void* g, void* l) {
  __builtin_amdgcn_global_load_lds(
      (const __attribute__((address_space(1))) unsigned int*)g,
      (__attribute__((address_space(3))) unsigned int*)l, 16, 0, 0);
}

__device__ __forceinline__ float block_sum(float v) {
#pragma unroll
  for (int o = 32; o; o >>= 1) v += __shfl_xor(v, o);
  __shared__ float red[4];
  if ((threadIdx.x & 63) == 0) red[threadIdx.x >> 6] = v;
  __syncthreads();
  return red[0] + red[1] + red[2] + red[3];
}

// weight-norm of in_v rows (dim E over C), store TRANSPOSED split pair Wt[c][e]
__global__ void wnorm_t_kernel(const float* __restrict__ v, const float* __restrict__ g,
                               u16* __restrict__ wth, u16* __restrict__ wtl) {
  const int e = blockIdx.x;
  const float* vr = v + (long)e * 1024;
  float ss = 0.f;
  for (int c = threadIdx.x; c < 1024; c += 256) { float t = vr[c]; ss += t * t; }
  const float tot = block_sum(ss);
  const float scl = g[e] / sqrtf(tot);
  for (int c = threadIdx.x; c < 1024; c += 256) {
    u16 hi, lo;
    split2(vr[c] * scl, hi, lo);
    wth[(long)c * 1024 + e] = hi;
    wtl[(long)c * 1024 + e] = lo;
  }
}

// weight-norm of out_v rows (dim C over E), natural layout single bf16 (B^T for out GEMM)
__global__ void wnorm_kernel(const float* __restrict__ v, const float* __restrict__ g,
                             u16* __restrict__ w) {
  const int c = blockIdx.x;
  const float* vr = v + (long)c * 1024;
  float ss = 0.f;
  for (int e = threadIdx.x; e < 1024; e += 256) { float t = vr[e]; ss += t * t; }
  const float tot = block_sum(ss);
  const float scl = g[c] / sqrtf(tot);
  for (int e = threadIdx.x; e < 1024; e += 256) w[(long)c * 1024 + e] = f2bf(vr[e] * scl);
}

// f32 -> (hi,lo) bf16 pair, vectorized by 4
__global__ void cvt_split_kernel(const float* __restrict__ in, u16* __restrict__ hi,
                                 u16* __restrict__ lo, long n4) {
  const long stride = (long)gridDim.x * blockDim.x;
  for (long i = (long)blockIdx.x * blockDim.x + threadIdx.x; i < n4; i += stride) {
    const float4 f = ((const float4*)in)[i];
    u16 h0, h1, h2, h3, l0, l1, l2, l3;
    split2(f.x, h0, l0); split2(f.y, h1, l1); split2(f.z, h2, l2); split2(f.w, h3, l3);
    uint2 hv, lv;
    hv.x = (unsigned)h0 | ((unsigned)h1 << 16); hv.y = (unsigned)h2 | ((unsigned)h3 << 16);
    lv.x = (unsigned)l0 | ((unsigned)l1 << 16); lv.y = (unsigned)l2 | ((unsigned)l3 << 16);
    ((uint2*)hi)[i] = hv;
    ((uint2*)lo)[i] = lv;
  }
}

// conv_feats [B,1024,196] -> y_ctx bf16 [B][1024][224] (K-pad 0) and
// y_t split pair [B][256][1024] (transposed, rows 196..255 zero)
__global__ void prep_y_kernel(const float* __restrict__ conv, u16* __restrict__ y_ctx,
                              u16* __restrict__ yth, u16* __restrict__ ytl) {
  const int b = blockIdx.x >> 4;
  const int e0 = (blockIdx.x & 15) << 6;
  __shared__ float tile[64 * 224];
  const float* cb = conv + ((long)b * 1024 + e0) * 196;
  for (int idx = threadIdx.x; idx < 64 * 224; idx += 256) {
    const int rr = idx / 224, vv = idx - rr * 224;
    const float val = (vv < 196) ? cb[(long)rr * 196 + vv] : 0.f;
    tile[idx] = val;
    y_ctx[((long)(b * 1024 + e0 + rr)) * 224 + vv] = f2bf(val);
  }
  __syncthreads();
  for (int idx = threadIdx.x; idx < 256 * 64; idx += 256) {
    const int vr = idx >> 6, c = idx & 63;
    const float val = (vr < 224) ? tile[c * 224 + vr] : 0.f;
    u16 hi, lo;
    split2(val, hi, lo);
    const long o = ((long)b * 256 + vr) * 1024 + e0 + c;
    yth[o] = hi;
    ytl[o] = lo;
  }
}

// rc[b][v] = sum_e in_b[e] * conv[b,e,v]   (f32, tiny)
__global__ void rc_kernel(const float* __restrict__ in_b, const float* __restrict__ conv,
                          float* __restrict__ rc) {
  const int b = blockIdx.x, v = threadIdx.x;
  float acc = 0.f;
  if (v < 196) {
    const float* cb = conv + (long)b * 1024 * 196 + v;
    for (int e = 0; e < 1024; ++e) acc += in_b[e] * cb[(long)e * 196];
  }
  rc[b * 256 + v] = (v < 196) ? acc : 0.f;
}

// scores [M][256] (f32, +rc, *sqrt(1/2)) -> attn f32 [M][196] + attn bf16 [M][224] (pad 0)
__global__ void softmax_kernel(const float* __restrict__ scores, const float* __restrict__ rc,
                               float* __restrict__ attn, u16* __restrict__ attn_bf) {
  const long row = (long)blockIdx.x * 4 + (threadIdx.x >> 6);
  const int lane = threadIdx.x & 63;
  const int b = (int)(row >> 10);
  const float* s = scores + row * 256;
  const float* rcb = rc + b * 256;
  float v0 = (s[lane] + rcb[lane]) * SQHF;
  float v1 = (s[64 + lane] + rcb[64 + lane]) * SQHF;
  float v2 = (s[128 + lane] + rcb[128 + lane]) * SQHF;
  float v3 = (lane < 4) ? (s[192 + lane] + rcb[192 + lane]) * SQHF : -1e30f;
  float mx = fmaxf(fmaxf(v0, v1), fmaxf(v2, v3));
#pragma unroll
  for (int o = 32; o; o >>= 1) mx = fmaxf(mx, __shfl_xor(mx, o));
  const float e0 = __expf(v0 - mx), e1 = __expf(v1 - mx), e2 = __expf(v2 - mx);
  const float e3 = (lane < 4) ? __expf(v3 - mx) : 0.f;
  float sm = e0 + e1 + e2 + e3;
#pragma unroll
  for (int o = 32; o; o >>= 1) sm += __shfl_xor(sm, o);
  const float inv = 1.f / sm;
  float* arow = attn + row * 196;
  arow[lane] = e0 * inv;
  arow[64 + lane] = e1 * inv;
  arow[128 + lane] = e2 * inv;
  if (lane < 4) arow[192 + lane] = e3 * inv;
  u16* brow = attn_bf + row * 224;
  brow[lane] = f2bf(e0 * inv);
  brow[64 + lane] = f2bf(e1 * inv);
  brow[128 + lane] = f2bf(e2 * inv);
  if (lane < 32) brow[192 + lane] = (lane < 4) ? f2bf(e3 * inv) : (u16)0;
}

// 128x128-tile bf16 MFMA GEMM, B^T-layout operands, optional split-bf16 (3-term) path.
// EPI: 1 = (acc+bias[col]+extra[row*1024+col])*scale -> f32
//      2 = f2bf(acc*scale) -> bf16
//      3 = acc -> f32      4 = f32 +=    5 = split pair store (out1=hi, out2=lo)
template <int EPI, int SPLIT>
__global__ __launch_bounds__(256) void gemm128(
    const u16* __restrict__ Ah, const u16* __restrict__ Al,
    const u16* __restrict__ Bh, const u16* __restrict__ Bl,
    int N, int K, int mTilesPerBatch, long bStride,
    const float* __restrict__ bias, const float* __restrict__ extra,
    float scale, void* __restrict__ out1, void* __restrict__ out2) {
  constexpr int TAH = 0, TAL = 4096, TBH = SPLIT ? 8192 : 4096, TBL = 12288;
  __shared__ __align__(16) u16 smem[SPLIT ? 16384 : 8192];

  const int numN = N >> 7;
  const int nwg = gridDim.x, bid = blockIdx.x;
  const int q = nwg >> 3, r = nwg & 7, xcd = bid & 7, l8 = bid >> 3;
  const int wg = (xcd < r ? xcd * (q + 1) : r * (q + 1) + (xcd - r) * q) + l8;
  const int mTile = wg / numN, nTile = wg - mTile * numN;
  const long rowBase = (long)mTile << 7;
  const int colBase = nTile << 7;

  const long bOff = mTilesPerBatch ? (long)(mTile / mTilesPerBatch) * bStride : 0;
  const u16* Agh = Ah + rowBase * K;
  const u16* Agl = SPLIT ? (Al + rowBase * K) : nullptr;
  const u16* Bgh = Bh + bOff + (long)colBase * K;
  const u16* Bgl = SPLIT ? (Bl + bOff + (long)colBase * K) : nullptr;

  const int tid = threadIdx.x;
  const int wave = tid >> 6, lane = tid & 63;
  const int wr = wave >> 1, wc = wave & 1;
  const int sr = wave * 16 + (lane >> 2);
  const int sc = (lane & 3) << 3;
  const int lr = lane & 15;
  const int lk = (lane >> 4) << 3;

  f32x4 acc[4][4];
#pragma unroll
  for (int m = 0; m < 4; ++m)
#pragma unroll
    for (int n = 0; n < 4; ++n) acc[m][n] = f32x4{0.f, 0.f, 0.f, 0.f};

  for (int k0 = 0; k0 < K; k0 += 32) {
#pragma unroll
    for (int i = 0; i < 2; ++i) {
      const long ro = (long)(i * 64 + sr) * K + k0 + sc;
      const int lo_ = i * 2048 + wave * 512;
      gload_lds16(Agh + ro, &smem[TAH + lo_]);
      gload_lds16(Bgh + ro, &smem[TBH + lo_]);
      if (SPLIT) {
        gload_lds16(Agl + ro, &smem[TAL + lo_]);
        gload_lds16(Bgl + ro, &smem[TBL + lo_]);
      }
    }
    __syncthreads();
    bf16x8 fah[4], fbh[4], fal[4], fbl[4];
#pragma unroll
    for (int m = 0; m < 4; ++m) {
      const int off = (wr * 64 + m * 16 + lr) * 32 + lk;
      fah[m] = __builtin_bit_cast(bf16x8, *(const u16x8*)&smem[TAH + off]);
      if (SPLIT) fal[m] = __builtin_bit_cast(bf16x8, *(const u16x8*)&smem[TAL + off]);
    }
#pragma unroll
    for (int n = 0; n < 4; ++n) {
      const int off = (wc * 64 + n * 16 + lr) * 32 + lk;
      fbh[n] = __builtin_bit_cast(bf16x8, *(const u16x8*)&smem[TBH + off]);
      if (SPLIT) fbl[n] = __builtin_bit_cast(bf16x8, *(const u16x8*)&smem[TBL + off]);
    }
#pragma unroll
    for (int m = 0; m < 4; ++m)
#pragma unroll
      for (int n = 0; n < 4; ++n) {
        acc[m][n] = __builtin_amdgcn_mfma_f32_16x16x32_bf16(fah[m], fbh[n], acc[m][n], 0, 0, 0);
        if (SPLIT) {
          acc[m][n] = __builtin_amdgcn_mfma_f32_16x16x32_bf16(fah[m], fbl[n], acc[m][n], 0, 0, 0);
          acc[m][n] = __builtin_amdgcn_mfma_f32_16x16x32_bf16(fal[m], fbh[n], acc[m][n], 0, 0, 0);
        }
      }
    __syncthreads();
  }

  const int rloc = (lane >> 4) << 2;
#pragma unroll
  for (int m = 0; m < 4; ++m) {
#pragma unroll
    for (int n = 0; n < 4; ++n) {
      const int col = colBase + wc * 64 + n * 16 + lr;
#pragma unroll
      for (int j = 0; j < 4; ++j) {
        const long row = rowBase + wr * 64 + m * 16 + rloc + j;
        const float v = acc[m][n][j];
        if (EPI == 1) {
          ((float*)out1)[row * (long)N + col] =
              (v + bias[col] + extra[row * 1024 + col]) * scale;
        } else if (EPI == 2) {
          ((u16*)out1)[row * (long)N + col] = f2bf(v * scale);
        } else if (EPI == 3) {
          ((float*)out1)[row * (long)N + col] = v;
        } else if (EPI == 4) {
          ((float*)out1)[row * (long)N + col] += v;
        } else if (EPI == 5) {
          u16 hi, lo;
          split2(v, hi, lo);
          ((u16*)out1)[row * (long)N + col] = hi;
          ((u16*)out2)[row * (long)N + col] = lo;
        }
      }
    }
  }
}

extern "C" void kernel_launch(void* const* d_in, const int* in_sizes, int n_in,
                              void* d_out, int out_size, void* d_ws, size_t ws_size,
                              hipStream_t stream) {
  (void)in_sizes; (void)n_in; (void)out_size; (void)ws_size;
  const float* x     = (const float*)d_in[0];
  const float* we    = (const float*)d_in[1];
  const float* conv  = (const float*)d_in[2];
  const float* in_v  = (const float*)d_in[3];
  const float* in_g  = (const float*)d_in[4];
  const float* in_b  = (const float*)d_in[5];
  const float* out_v = (const float*)d_in[6];
  const float* out_g = (const float*)d_in[7];
  const float* out_b = (const float*)d_in[8];
  float* out  = (float*)d_out;
  float* attn = out + 33554432l;  // B*L*C floats, then B*L*196

  char* ws = (char*)d_ws;
  // region P1 [0, 134MB): x hi/lo pair, then we hi/lo pair, then attn_bf + ctx_bf
  u16* P1h   = (u16*)(ws);
  u16* P1l   = (u16*)(ws + 67108864l);
  u16* attbf = (u16*)(ws);                 // [32768][224] after score passes
  u16* ctxbf = (u16*)(ws + 16777216l);     // [32768][1024]
  u16* yth   = (u16*)(ws + 134217728l);    // [32][256][1024]
  u16* ytl   = (u16*)(ws + 150994944l);
  u16* zth   = (u16*)(ws + 167772160l);    // Zi^T pair [32][256][1024]
  u16* ztl   = (u16*)(ws + 184549376l);
  u16* wth   = (u16*)(ws + 201326592l);    // Wt pair [1024][1024]
  u16* wtl   = (u16*)(ws + 203423744l);
  u16* yctx  = (u16*)(ws + 205520896l);    // [32][1024][224]
  u16* wo    = (u16*)(ws + 220200960l);    // [1024][1024]
  float* rc  = (float*)(ws + 222298112l);  // [32][256]
  float* scores = out;                     // f32 scratch [32768][256] in out region

  wnorm_t_kernel<<<1024, 256, 0, stream>>>(in_v, in_g, wth, wtl);
  wnorm_kernel<<<1024, 256, 0, stream>>>(out_v, out_g, wo);
  prep_y_kernel<<<512, 256, 0, stream>>>(conv, yctx, yth, ytl);
  rc_kernel<<<32, 256, 0, stream>>>(in_b, conv, rc);
  cvt_split_kernel<<<2048, 256, 0, stream>>>(x, P1h, P1l, 8388608l);
  // Zi^T[v,c] = sum_e y[b,e,v] * Wi[e,c]  -> split pair   (M=8192, N=1024, K=1024)
  gemm128<5, 1><<<512, 256, 0, stream>>>(yth, ytl, wth, wtl, 1024, 1024, 0, 0,
                                         nullptr, nullptr, 1.f, zth, ztl);
  // scores pass 1: x @ Zi   (M=32768, N=256, K=1024; B batched per 8 m-tiles)
  gemm128<3, 1><<<512, 256, 0, stream>>>(P1h, P1l, zth, ztl, 256, 1024, 8, 262144l,
                                         nullptr, nullptr, 1.f, scores, nullptr);
  cvt_split_kernel<<<2048, 256, 0, stream>>>(we, P1h, P1l, 8388608l);
  // scores pass 2: += we @ y
  gemm128<4, 1><<<512, 256, 0, stream>>>(P1h, P1l, yth, ytl, 256, 1024, 8, 262144l,
                                         nullptr, nullptr, 1.f, scores, nullptr);
  softmax_kernel<<<8192, 256, 0, stream>>>(scores, rc, attn, attbf);
  // ctx = 14 * attn @ y^T -> bf16   (M=32768, N=1024, K=224)
  gemm128<2, 0><<<2048, 256, 0, stream>>>(attbf, nullptr, yctx, nullptr, 1024, 224, 8,
                                          229376l, nullptr, nullptr, 14.f, ctxbf, nullptr);
  // out = (ctx @ Wo^T + out_b + x) * sqrt(0.5) -> f32
  gemm128<1, 0><<<2048, 256, 0, stream>>>(ctxbf, nullptr, wo, nullptr, 1024, 1024, 0, 0,
                                          out_b, x, SQHF, out, nullptr);
}

// Round 2
// 373.755 us; speedup vs baseline: 1.8349x; 1.8349x over previous
//
#include <hip/hip_runtime.h>
#include <hip/hip_bf16.h>

typedef unsigned short u16;
typedef __bf16 bf16x8 __attribute__((ext_vector_type(8)));
typedef unsigned short u16x8 __attribute__((ext_vector_type(8)));
typedef float f32x4 __attribute__((ext_vector_type(4)));

#define SQHF 0.70710678118654752440f

__device__ __forceinline__ u16 f2bf(float f) {
  __hip_bfloat16 h = __float2bfloat16(f);
  return __builtin_bit_cast(u16, h);
}
__device__ __forceinline__ float bf2f(u16 u) {
  unsigned x = ((unsigned)u) << 16;
  return __builtin_bit_cast(float, x);
}
__device__ __forceinline__ void split2(float v, u16& hi, u16& lo) {
  hi = f2bf(v);
  lo = f2bf(v - bf2f(hi));
}

// async global->LDS, 16B per lane; LDS dest is wave-uniform base + lane*16
__device__ __forceinline__ void gload_lds16(const void* g, void* l) {
  __builtin_amdgcn_global_load_lds(
      (const __attribute__((address_space(1))) unsigned int*)g,
      (__attribute__((address_space(3))) unsigned int*)l, 16, 0, 0);
}

__device__ __forceinline__ float block_sum(float v) {
#pragma unroll
  for (int o = 32; o; o >>= 1) v += __shfl_xor(v, o);
  __shared__ float red[4];
  if ((threadIdx.x & 63) == 0) red[threadIdx.x >> 6] = v;
  __syncthreads();
  return red[0] + red[1] + red[2] + red[3];
}

// weight-norm of in_v rows (dim E over C), store TRANSPOSED split pair Wt[c][e]
__global__ void wnorm_t_kernel(const float* __restrict__ v, const float* __restrict__ g,
                               u16* __restrict__ wth, u16* __restrict__ wtl) {
  const int e = blockIdx.x;
  const float* vr = v + (long)e * 1024;
  float ss = 0.f;
  for (int c = threadIdx.x; c < 1024; c += 256) { float t = vr[c]; ss += t * t; }
  const float tot = block_sum(ss);
  const float scl = g[e] / sqrtf(tot);
  for (int c = threadIdx.x; c < 1024; c += 256) {
    u16 hi, lo;
    split2(vr[c] * scl, hi, lo);
    wth[(long)c * 1024 + e] = hi;
    wtl[(long)c * 1024 + e] = lo;
  }
}

// weight-norm of out_v rows (dim C over E), natural layout single bf16 (A for Zo GEMM)
__global__ void wnorm_kernel(const float* __restrict__ v, const float* __restrict__ g,
                             u16* __restrict__ w) {
  const int c = blockIdx.x;
  const float* vr = v + (long)c * 1024;
  float ss = 0.f;
  for (int e = threadIdx.x; e < 1024; e += 256) { float t = vr[e]; ss += t * t; }
  const float tot = block_sum(ss);
  const float scl = g[c] / sqrtf(tot);
  for (int e = threadIdx.x; e < 1024; e += 256) w[(long)c * 1024 + e] = f2bf(vr[e] * scl);
}

// conv_feats [B,1024,196] -> y_t split pair written into concat buffer cols 1024..2047
// (btc layout: [32][256][2048], rows v in [196,256) zero)
__global__ void prep_y_kernel(const float* __restrict__ conv, u16* __restrict__ bth,
                              u16* __restrict__ btl) {
  const int b = blockIdx.x >> 4;
  const int e0 = (blockIdx.x & 15) << 6;
  __shared__ float tile[64 * 224];
  const float* cb = conv + ((long)b * 1024 + e0) * 196;
  for (int idx = threadIdx.x; idx < 64 * 224; idx += 256) {
    const int rr = idx / 224, vv = idx - rr * 224;
    tile[idx] = (vv < 196) ? cb[(long)rr * 196 + vv] : 0.f;
  }
  __syncthreads();
  for (int idx = threadIdx.x; idx < 256 * 64; idx += 256) {
    const int vr = idx >> 6, c = idx & 63;
    const float val = (vr < 224) ? tile[c * 224 + vr] : 0.f;
    u16 hi, lo;
    split2(val, hi, lo);
    const long o = ((long)b * 256 + vr) * 2048 + 1024 + e0 + c;
    bth[o] = hi;
    btl[o] = lo;
  }
}

// rc[b][v] = sum_e in_b[e] * y[b,e,v], from transposed split y (coalesced over e)
__global__ void rc_kernel(const float* __restrict__ in_b, const u16* __restrict__ bth,
                          const u16* __restrict__ btl, float* __restrict__ rc) {
  const int b = blockIdx.x / 49;
  const int v = (blockIdx.x % 49) * 4 + (threadIdx.x >> 6);
  const int lane = threadIdx.x & 63;
  const long base = ((long)b * 256 + v) * 2048 + 1024;
  float acc = 0.f;
  for (int e = lane; e < 1024; e += 64)
    acc += in_b[e] * (bf2f(bth[base + e]) + bf2f(btl[base + e]));
#pragma unroll
  for (int o = 32; o; o >>= 1) acc += __shfl_xor(acc, o);
  if (lane == 0) rc[b * 256 + v] = acc;
}

// scores [M][256] (f32, +rc, *sqrt(1/2)) -> attn f32 [M][196] + attn bf16 [M][256] (pad 0)
__global__ void softmax_kernel(const float* __restrict__ scores, const float* __restrict__ rc,
                               float* __restrict__ attn, u16* __restrict__ attn_bf) {
  const long row = (long)blockIdx.x * 4 + (threadIdx.x >> 6);
  const int lane = threadIdx.x & 63;
  const int b = (int)(row >> 10);
  const float* s = scores + row * 256;
  const float* rcb = rc + b * 256;
  float v0 = (s[lane] + rcb[lane]) * SQHF;
  float v1 = (s[64 + lane] + rcb[64 + lane]) * SQHF;
  float v2 = (s[128 + lane] + rcb[128 + lane]) * SQHF;
  float v3 = (lane < 4) ? (s[192 + lane] + rcb[192 + lane]) * SQHF : -1e30f;
  float mx = fmaxf(fmaxf(v0, v1), fmaxf(v2, v3));
#pragma unroll
  for (int o = 32; o; o >>= 1) mx = fmaxf(mx, __shfl_xor(mx, o));
  const float e0 = __expf(v0 - mx), e1 = __expf(v1 - mx), e2 = __expf(v2 - mx);
  const float e3 = (lane < 4) ? __expf(v3 - mx) : 0.f;
  float sm = e0 + e1 + e2 + e3;
#pragma unroll
  for (int o = 32; o; o >>= 1) sm += __shfl_xor(sm, o);
  const float inv = 1.f / sm;
  float* arow = attn + row * 196;
  arow[lane] = e0 * inv;
  arow[64 + lane] = e1 * inv;
  arow[128 + lane] = e2 * inv;
  if (lane < 4) arow[192 + lane] = e3 * inv;
  u16* brow = attn_bf + row * 256;
  brow[lane] = f2bf(e0 * inv);
  brow[64 + lane] = f2bf(e1 * inv);
  brow[128 + lane] = f2bf(e2 * inv);
  brow[192 + lane] = (lane < 4) ? f2bf(e3 * inv) : (u16)0;
}

// 128x128-tile bf16 MFMA GEMM.
//  AF32=1: A staged as f32 (XOR-swizzled tile), split to bf16 hi/lo in-register;
//          A source = Af0 for k<kSw else Af1 (both row-major ldA f32).
//  SPLIT=1: 3-term split-bf16 product (A,B hi/lo pairs).
//  aTilesMod: if >0, A row-tile index = mTile % aTilesMod (replicated A).
//  mTilesPerBatch/bStride: batch the B operand per group of m-tiles.
// EPI: 1 = (acc+bias[col]+extra[row*ldOut+col])*scale -> f32
//      2 = f2bf(acc*scale) -> bf16
//      3 = acc -> f32      5 = split pair store (out1=hi, out2=lo)
template <int EPI, int SPLIT, int AF32>
__global__ __launch_bounds__(256) void gemm128(
    const u16* __restrict__ Ah, const u16* __restrict__ Al,
    const float* __restrict__ Af0, const float* __restrict__ Af1, int kSw,
    const u16* __restrict__ Bh, const u16* __restrict__ Bl,
    int N, int K, int ldA, int ldB, int ldOut,
    int mTilesPerBatch, long bStride, int aTilesMod,
    const float* __restrict__ bias, const float* __restrict__ extra,
    float scale, void* __restrict__ out1, void* __restrict__ out2) {
  constexpr int TA = 0;                 // AF32: f32 tile [128][32] = 8192 u16 slots
  constexpr int TAH = 0, TAL = 4096;    // bf16 pair tiles
  constexpr int TBH = (AF32 || SPLIT) ? 8192 : 4096;
  constexpr int TBL = 12288;
  constexpr int SM = (AF32 || SPLIT) ? 16384 : 8192;
  __shared__ __align__(16) u16 smem[SM];

  const int numN = N >> 7;
  const int nwg = gridDim.x, bid = blockIdx.x;
  const int q = nwg >> 3, r = nwg & 7, xcd = bid & 7, l8 = bid >> 3;
  const int wg = (xcd < r ? xcd * (q + 1) : r * (q + 1) + (xcd - r) * q) + l8;
  const int mTile = wg / numN, nTile = wg - mTile * numN;
  const long rowBase = (long)mTile << 7;
  const int colBase = nTile << 7;
  const int aTile = aTilesMod ? (mTile % aTilesMod) : mTile;
  const long aRowBase = (long)aTile << 7;

  const long bOff = mTilesPerBatch ? (long)(mTile / mTilesPerBatch) * bStride : 0;
  const u16* Agh = AF32 ? nullptr : (Ah + aRowBase * ldA);
  const u16* Agl = (!AF32 && SPLIT) ? (Al + aRowBase * ldA) : nullptr;
  const u16* Bgh = Bh + bOff + (long)colBase * ldB;
  const u16* Bgl = SPLIT ? (Bl + bOff + (long)colBase * ldB) : nullptr;

  const int tid = threadIdx.x;
  const int wave = tid >> 6, lane = tid & 63;
  const int wr = wave >> 1, wc = wave & 1;
  const int sr = wave * 16 + (lane >> 2);
  const int sc = (lane & 3) << 3;
  const int lr = lane & 15;
  const int lk = (lane >> 4) << 3;

  f32x4 acc[4][4];
#pragma unroll
  for (int m = 0; m < 4; ++m)
#pragma unroll
    for (int n = 0; n < 4; ++n) acc[m][n] = f32x4{0.f, 0.f, 0.f, 0.f};

  for (int k0 = 0; k0 < K; k0 += 32) {
    if (AF32) {
      const float* As = (k0 < kSw) ? (Af0 + aRowBase * (long)ldA + k0)
                                   : (Af1 + aRowBase * (long)ldA + (k0 - kSw));
      const int rr = tid >> 3;
#pragma unroll
      for (int i = 0; i < 4; ++i) {
        const int row = i * 32 + rr;
        const int csw = (((tid & 7) ^ (row & 7)) << 2);  // XOR-swizzled f32 col
        gload_lds16(As + (long)row * ldA + csw, &smem[TA + i * 2048 + wave * 512]);
      }
#pragma unroll
      for (int i = 0; i < 2; ++i) {
        const long ro = (long)(i * 64 + sr) * ldB + k0 + sc;
        const int lo_ = i * 2048 + wave * 512;
        gload_lds16(Bgh + ro, &smem[TBH + lo_]);
        gload_lds16(Bgl + ro, &smem[TBL + lo_]);
      }
    } else {
#pragma unroll
      for (int i = 0; i < 2; ++i) {
        const long roA = (long)(i * 64 + sr) * ldA + k0 + sc;
        const long roB = (long)(i * 64 + sr) * ldB + k0 + sc;
        const int lo_ = i * 2048 + wave * 512;
        gload_lds16(Agh + roA, &smem[TAH + lo_]);
        gload_lds16(Bgh + roB, &smem[TBH + lo_]);
        if (SPLIT) {
          gload_lds16(Agl + roA, &smem[TAL + lo_]);
          gload_lds16(Bgl + roB, &smem[TBL + lo_]);
        }
      }
    }
    __syncthreads();

    bf16x8 fah[4], fbh[4], fal[4], fbl[4];
    if (AF32) {
      const char* smemb = (const char*)smem;
#pragma unroll
      for (int m = 0; m < 4; ++m) {
        const int row = wr * 64 + m * 16 + lr;
        const int xr = (row & 7) << 4;
        const char* rp = smemb + row * 128;
        const f32x4 p0 = *(const f32x4*)(rp + (((lk << 2)) ^ xr));
        const f32x4 p1 = *(const f32x4*)(rp + (((lk << 2) + 16) ^ xr));
        const float fv[8] = {p0.x, p0.y, p0.z, p0.w, p1.x, p1.y, p1.z, p1.w};
        u16x8 hv, lv;
#pragma unroll
        for (int j = 0; j < 8; ++j) {
          const u16 h = f2bf(fv[j]);
          hv[j] = h;
          lv[j] = f2bf(fv[j] - bf2f(h));
        }
        fah[m] = __builtin_bit_cast(bf16x8, hv);
        fal[m] = __builtin_bit_cast(bf16x8, lv);
      }
    } else {
#pragma unroll
      for (int m = 0; m < 4; ++m) {
        const int off = (wr * 64 + m * 16 + lr) * 32 + lk;
        fah[m] = __builtin_bit_cast(bf16x8, *(const u16x8*)&smem[TAH + off]);
        if (SPLIT) fal[m] = __builtin_bit_cast(bf16x8, *(const u16x8*)&smem[TAL + off]);
      }
    }
#pragma unroll
    for (int n = 0; n < 4; ++n) {
      const int off = (wc * 64 + n * 16 + lr) * 32 + lk;
      fbh[n] = __builtin_bit_cast(bf16x8, *(const u16x8*)&smem[TBH + off]);
      if (SPLIT) fbl[n] = __builtin_bit_cast(bf16x8, *(const u16x8*)&smem[TBL + off]);
    }
#pragma unroll
    for (int m = 0; m < 4; ++m)
#pragma unroll
      for (int n = 0; n < 4; ++n) {
        acc[m][n] = __builtin_amdgcn_mfma_f32_16x16x32_bf16(fah[m], fbh[n], acc[m][n], 0, 0, 0);
        if (SPLIT) {
          acc[m][n] = __builtin_amdgcn_mfma_f32_16x16x32_bf16(fah[m], fbl[n], acc[m][n], 0, 0, 0);
          acc[m][n] = __builtin_amdgcn_mfma_f32_16x16x32_bf16(fal[m], fbh[n], acc[m][n], 0, 0, 0);
        }
      }
    __syncthreads();
  }

  const int rloc = (lane >> 4) << 2;
#pragma unroll
  for (int m = 0; m < 4; ++m) {
#pragma unroll
    for (int n = 0; n < 4; ++n) {
      const int col = colBase + wc * 64 + n * 16 + lr;
#pragma unroll
      for (int j = 0; j < 4; ++j) {
        const long row = rowBase + wr * 64 + m * 16 + rloc + j;
        const float v = acc[m][n][j];
        if (EPI == 1) {
          ((float*)out1)[row * (long)ldOut + col] =
              (v + bias[col] + extra[row * (long)ldOut + col]) * scale;
        } else if (EPI == 2) {
          ((u16*)out1)[row * (long)ldOut + col] = f2bf(v * scale);
        } else if (EPI == 3) {
          ((float*)out1)[row * (long)ldOut + col] = v;
        } else if (EPI == 5) {
          u16 hi, lo;
          split2(v, hi, lo);
          ((u16*)out1)[row * (long)ldOut + col] = hi;
          ((u16*)out2)[row * (long)ldOut + col] = lo;
        }
      }
    }
  }
}

extern "C" void kernel_launch(void* const* d_in, const int* in_sizes, int n_in,
                              void* d_out, int out_size, void* d_ws, size_t ws_size,
                              hipStream_t stream) {
  (void)in_sizes; (void)n_in; (void)out_size; (void)ws_size;
  const float* x     = (const float*)d_in[0];
  const float* we    = (const float*)d_in[1];
  const float* conv  = (const float*)d_in[2];
  const float* in_v  = (const float*)d_in[3];
  const float* in_g  = (const float*)d_in[4];
  const float* in_b  = (const float*)d_in[5];
  const float* out_v = (const float*)d_in[6];
  const float* out_g = (const float*)d_in[7];
  const float* out_b = (const float*)d_in[8];
  float* out  = (float*)d_out;
  float* attn = out + 33554432l;  // B*L*C floats, then B*L*196

  char* ws = (char*)d_ws;
  u16* btch  = (u16*)(ws);                  // [32][256][2048]: cols 0..1023 Zi^T, 1024.. y_t (hi)
  u16* btcl  = (u16*)(ws + 33554432l);      // same, lo
  u16* wth   = (u16*)(ws + 67108864l);      // Wt pair [1024][1024]
  u16* wtl   = (u16*)(ws + 69206016l);
  u16* wo    = (u16*)(ws + 71303168l);      // Wo bf16 [1024][1024]
  u16* zo    = (u16*)(ws + 73400320l);      // Zo bf16 [32][1024][256] (x14 folded)
  u16* attbf = (u16*)(ws + 90177536l);      // [32768][256]
  float* rc  = (float*)(ws + 106954752l);   // [32][256]
  float* scores = out;                      // f32 scratch [32768][256] in out region

  wnorm_t_kernel<<<1024, 256, 0, stream>>>(in_v, in_g, wth, wtl);
  wnorm_kernel<<<1024, 256, 0, stream>>>(out_v, out_g, wo);
  prep_y_kernel<<<512, 256, 0, stream>>>(conv, btch, btcl);
  rc_kernel<<<1568, 256, 0, stream>>>(in_b, btch, btcl, rc);
  // Zi^T[b*256+v][c] = sum_e y_t[b][v][e] * Wt[c][e] -> split pair into btc cols 0..1023
  // (M=8192, N=1024, K=1024; A = y_t inside concat buffer)
  gemm128<5, 1, 0><<<512, 256, 0, stream>>>(
      btch + 1024, btcl + 1024, nullptr, nullptr, 0, wth, wtl,
      1024, 1024, 2048, 1024, 2048, 0, 0, 0, nullptr, nullptr, 1.f, btch, btcl);
  // scores = [x|we] @ [Zi;y]  (M=32768, N=256, K=2048; A f32 in-register split)
  gemm128<3, 1, 1><<<512, 256, 0, stream>>>(
      nullptr, nullptr, x, we, 1024, btch, btcl,
      256, 2048, 1024, 2048, 256, 8, 524288l, 0, nullptr, nullptr, 1.f, scores, nullptr);
  softmax_kernel<<<8192, 256, 0, stream>>>(scores, rc, attn, attbf);
  // Zo[b*1024+c][v] = 14 * sum_e Wo[c][e] * y_t[b][v][e] -> bf16
  // (M=32768, N=256, K=1024; A=Wo replicated per batch, B=y_t hi batched)
  gemm128<2, 0, 0><<<512, 256, 0, stream>>>(
      wo, nullptr, nullptr, nullptr, 0, btch + 1024, nullptr,
      256, 1024, 1024, 2048, 256, 8, 524288l, 8, nullptr, nullptr, 14.f, zo, nullptr);
  // out = (attn_bf @ Zo^T + out_b + x) * sqrt(0.5)  (M=32768, N=1024, K=256)
  gemm128<1, 0, 0><<<2048, 256, 0, stream>>>(
      attbf, nullptr, nullptr, nullptr, 0, zo, nullptr,
      1024, 256, 256, 256, 1024, 8, 262144l, 0, out_b, x, SQHF, out, nullptr);
}